// Round 12
// baseline (236.170 us; speedup 1.0000x reference)
//
#include <hip/hip_runtime.h>
#include <hip/hip_bf16.h>

// FeatureAdaption R12: 16x16 core (R7-verified fragments/A-paths, f32x4 acc),
// K-split(2), BK=32 subtiles, [p][co][e] conflict-free LDS (no XOR),
// fragment-native coalesced partials + matching reduces, launch_bounds(256,3).
// conv1(256->256) -> conv2(256->72)=offsets -> deform conv v1 + ReLU.
// B=8, C=256, H=W=64, dg=4, K=9 taps, K_total=2304 = 72 subtiles of 32.

typedef __attribute__((ext_vector_type(8))) short bf16x8;
typedef __attribute__((ext_vector_type(4))) float f32x4;

static __device__ __forceinline__ ushort f2bf(float f) {
  __hip_bfloat16 h = __float2bfloat16(f);
  return *reinterpret_cast<ushort*>(&h);
}
static __device__ __forceinline__ float bf2f(ushort u) {
  union { uint u32; float f; } cv;
  cv.u32 = ((uint)u) << 16;
  return cv.f;
}

// ---------------- weight prep: [tk 72][p 4][co][e 8] bf16 ----------------
// k within subtile = p*8+e; channel-in-tap cc = (tk&1)*32 + p*8 + e.
// conv : tap ti = tk>>1 = kk*4+chunk  (ci = chunk*64+cc)
// deform: tap ti = g*9+kkt            (c = cc within group)
__global__ __launch_bounds__(256) void prep_weights(
    const float* __restrict__ w1, const float* __restrict__ w2,
    const float* __restrict__ wd,
    ushort* __restrict__ wt1, ushort* __restrict__ wt2,
    ushort* __restrict__ wtd) {
  const int N1 = 72 * 4 * 256 * 8;   // 589824
  const int N2 = 72 * 4 * 128 * 8;   // 294912 (co padded 72->128, zeros)
  const int N3 = 72 * 4 * 256 * 8;   // 589824
  int total = N1 + N2 + N3;
  for (int i = blockIdx.x * 256 + threadIdx.x; i < total; i += gridDim.x * 256) {
    if (i < N1) {
      int e = i & 7, co = (i >> 3) & 255, p = (i >> 11) & 3, tk = i >> 13;
      int ti = tk >> 1, half = tk & 1;
      int kk = ti >> 2, ch = ti & 3;
      int cc = half * 32 + p * 8 + e;
      wt1[i] = f2bf(w1[(co * 256 + ch * 64 + cc) * 9 + kk]);
    } else if (i < N1 + N2) {
      int d = i - N1;
      int e = d & 7, co = (d >> 3) & 127, p = (d >> 10) & 3, tk = d >> 12;
      int ti = tk >> 1, half = tk & 1;
      int kk = ti >> 2, ch = ti & 3;
      int cc = half * 32 + p * 8 + e;
      wt2[d] = (co < 72) ? f2bf(w2[(co * 256 + ch * 64 + cc) * 9 + kk])
                         : (ushort)0;
    } else {
      int d = i - N1 - N2;
      int e = d & 7, co = (d >> 3) & 255, p = (d >> 11) & 3, tk = d >> 13;
      int ti = tk >> 1, half = tk & 1;
      int g = ti / 9, kkt = ti - g * 9;
      int c = half * 32 + p * 8 + e;
      wtd[d] = f2bf(wd[(co * 256 + g * 64 + c) * 9 + kkt]);
    }
  }
}

// ---------------- x -> channel-last grouped bf16 (verified R3-R11) -----------
__global__ __launch_bounds__(256) void transpose_x(
    const float* __restrict__ x, ushort* __restrict__ xt) {
  int id = blockIdx.x;
  int y = id & 63, bg = id >> 6;
  int c = threadIdx.x & 63, xi = threadIdx.x >> 6;
  const float* ip = x + (((size_t)bg) << 18) + ((size_t)c << 12) + y * 64;
  ushort* op = xt + (((size_t)bg) << 18) + (size_t)y * 4096 + c;
#pragma unroll
  for (int j = 0; j < 16; ++j) {
    int xx = xi * 16 + j;
    op[(size_t)xx * 64] = f2bf(ip[xx]);
  }
}

// ---------------- 16x16 MFMA kernel: K-split(2), BK=32, frag partials --------
// Grid 1024 = 8b x 64h x 2khalf [XCD swizzled -> batch b == XCD id].
// Block: 4 waves x 16px = one h row (64 px); co tile = NFR*16 (all waves).
// Per khalf: 18 taps = 36 BK=32 subtiles, LDS [p][co][e] dbuf (conflict-free).
// Partials: par[((b*64+h)*4+wv)*(NFR*4*64) + (nf*4+ri)*64 + lane] bf16
// -> every store instruction is one contiguous 128B wave-write.
template <int MODE, int NFR>
__global__ __launch_bounds__(256, 3) void fa_mfma10(
    const ushort* __restrict__ inT,  // [bg][4096 px][64 c] bf16
    const float* __restrict__ off,   // [B][72][64][64] f32 (MODE 1)
    const ushort* __restrict__ wBs,  // [72][4][CO_TILE][8] bf16
    ushort* __restrict__ parA,       // partial khalf 0
    ushort* __restrict__ parB) {     // partial khalf 1
  constexpr int CO_TILE = NFR * 16;
  constexpr int SUB_U = CO_TILE * 32;            // ushorts per subtile
  constexpr int NCALLS = (SUB_U * 2) / 4096;     // 16B x 256thr per call
  constexpr int NRN = (MODE == 1) ? 8 : 2;
  __shared__ __align__(16) ushort Blds[2][SUB_U];

  int id = blockIdx.x;
  int id2 = (id & 7) * 128 + (id >> 3);          // XCD swizzle (1024 = 8*128)
  int khalf = id2 & 1;
  int rest = id2 >> 1;                           // [0,512)
  int h = rest & 63, b = rest >> 6;              // h [0,64), b [0,8)
  int t = threadIdx.x;
  int wv = t >> 6, lane = t & 63;
  int ml = lane & 15, kc = lane >> 4;
  int pcol = wv * 16 + ml;                       // this lane's pixel column
  ushort* par = khalf ? parB : parA;

  auto stage = [&](int s, int buf) {             // s = local subtile [0,36)
    int tk = khalf * 36 + s;
    const char* src0 = (const char*)wBs + (size_t)tk * (SUB_U * 2) + t * 16;
    ushort* dst0 = &Blds[buf][t * 8];
#pragma unroll
    for (int m = 0; m < NCALLS; ++m) {
      __builtin_amdgcn_global_load_lds(
          (const __attribute__((address_space(1))) void*)(src0 + m * 4096),
          (__attribute__((address_space(3))) void*)(dst0 + m * 2048), 16, 0, 0);
    }
  };

  const bf16x8 bz = {0, 0, 0, 0, 0, 0, 0, 0};
  bf16x8 aCur0, aCur1;                           // tap's two 32-chan frags
  bf16x8 rN[NRN];
  float wsv[4];
  float2 offA;

  // ---- MODE 0: direct conv A-path (R7 verbatim) ----
  auto issueA0 = [&](int tap) {
    int kk = tap >> 2, chunk = tap & 3;
    int ky = kk / 3, kx = kk - ky * 3;
    int gy = h + ky - 1, gx = pcol + kx - 1;
    bool inb = (gy >= 0) & (gy < 64) & (gx >= 0) & (gx < 64);
    const ushort* p =
        inT + ((((size_t)(b * 4 + chunk) << 12) + gy * 64 + gx) << 6) + kc * 8;
    rN[0] = bz;
    rN[1] = bz;
    if (inb) {
      rN[0] = *(const bf16x8*)p;
      rN[1] = *(const bf16x8*)(p + 32);
    }
  };
  auto finishA0 = [&]() {
    aCur0 = rN[0];
    aCur1 = rN[1];
  };

  // ---- MODE 1: deform A-path (R7 verbatim) ----
  auto loadOff = [&](int tap) {
    int g = tap / 9, kkt = tap - 9 * (tap / 9);
    int ch = g * 18 + kkt * 2;
    const float* offp = off + (((size_t)b * 72 + ch) << 12) + h * 64 + pcol;
    offA.x = offp[0];
    offA.y = offp[4096];
  };
  auto issueA1 = [&](int tap) {
    int g = tap / 9, kkt = tap - 9 * (tap / 9);
    int ky = kkt / 3, kx = kkt - ky * 3;
    const ushort* base = inT + (((size_t)(b * 4 + g)) << 18) + kc * 8;
    float py = (float)(h + ky - 1) + offA.x;
    float pxf = (float)(pcol + kx - 1) + offA.y;
    float y0f = floorf(py), x0f = floorf(pxf);
    float wy1 = py - y0f, wx1 = pxf - x0f;
    float wy0 = 1.f - wy1, wx0 = 1.f - wx1;
    int y0 = (int)y0f, x0i = (int)x0f;
    int y1 = y0 + 1, x1i = x0i + 1;
    bool vy0 = (y0 >= 0) & (y0 < 64);
    bool vy1 = (y1 >= 0) & (y1 < 64);
    bool vx0 = (x0i >= 0) & (x0i < 64);
    bool vx1 = (x1i >= 0) & (x1i < 64);
    wsv[0] = (vy0 & vx0) ? wy0 * wx0 : 0.f;
    wsv[1] = (vy0 & vx1) ? wy0 * wx1 : 0.f;
    wsv[2] = (vy1 & vx0) ? wy1 * wx0 : 0.f;
    wsv[3] = (vy1 & vx1) ? wy1 * wx1 : 0.f;
    int yc0 = min(max(y0, 0), 63), yc1 = min(max(y1, 0), 63);
    int xc0 = min(max(x0i, 0), 63), xc1 = min(max(x1i, 0), 63);
    const ushort* p00 = base + ((yc0 * 64 + xc0) << 6);
    const ushort* p01 = base + ((yc0 * 64 + xc1) << 6);
    const ushort* p10 = base + ((yc1 * 64 + xc0) << 6);
    const ushort* p11 = base + ((yc1 * 64 + xc1) << 6);
    rN[0] = *(const bf16x8*)p00;
    rN[1] = *(const bf16x8*)(p00 + 32);
    rN[2] = *(const bf16x8*)p01;
    rN[3] = *(const bf16x8*)(p01 + 32);
    rN[4] = *(const bf16x8*)p10;
    rN[5] = *(const bf16x8*)(p10 + 32);
    rN[6] = *(const bf16x8*)p11;
    rN[7] = *(const bf16x8*)(p11 + 32);
  };
  auto finishA1 = [&]() {
    float w00 = wsv[0], w01 = wsv[1], w10 = wsv[2], w11 = wsv[3];
#pragma unroll
    for (int ks = 0; ks < 2; ++ks) {
      bf16x8 q00 = rN[0 + ks], q01 = rN[2 + ks];
      bf16x8 q10 = rN[4 + ks], q11 = rN[6 + ks];
      bf16x8 av;
#pragma unroll
      for (int jj = 0; jj < 8; ++jj) {
        float v = w00 * bf2f((ushort)q00[jj]) + w01 * bf2f((ushort)q01[jj]) +
                  w10 * bf2f((ushort)q10[jj]) + w11 * bf2f((ushort)q11[jj]);
        av[jj] = (short)f2bf(v);
      }
      if (ks == 0) aCur0 = av; else aCur1 = av;
    }
  };

  f32x4 acc[NFR];
#pragma unroll
  for (int j = 0; j < NFR; ++j) acc[j] = (f32x4){0.f, 0.f, 0.f, 0.f};

  auto domfma = [&](bf16x8 a, int buf) {
    __builtin_amdgcn_s_setprio(1);
#pragma unroll
    for (int nf = 0; nf < NFR; ++nf) {
      bf16x8 bq = *(const bf16x8*)&Blds[buf][(kc * CO_TILE + nf * 16 + ml) * 8];
      acc[nf] = __builtin_amdgcn_mfma_f32_16x16x32_bf16(a, bq, acc[nf], 0, 0, 0);
    }
    __builtin_amdgcn_s_setprio(0);
  };

  const int tap0 = khalf * 18;

  // prologue: A(tap0) built, subtile 0 staged
  if (MODE == 1) {
    loadOff(tap0);
    issueA1(tap0);
    loadOff(tap0 + 1);
    finishA1();
  } else {
    issueA0(tap0);
    finishA0();
  }
  stage(0, 0);
  __syncthreads();

  for (int tp = 0; tp < 18; ++tp) {
    int tap = tap0 + tp;
    // even phase: subtile 2tp (buf0); prefetch subtile 2tp+1 and next tap's A
    if (2 * tp + 1 < 36) stage(2 * tp + 1, 1);
    if (tp < 17) { if (MODE == 1) issueA1(tap + 1); else issueA0(tap + 1); }
    if (MODE == 1 && tp < 16) loadOff(tap + 2);
    domfma(aCur0, 0);
    __syncthreads();
    // odd phase: subtile 2tp+1 (buf1); prefetch subtile 2tp+2; finish next A
    if (2 * tp + 2 < 36) stage(2 * tp + 2, 0);
    domfma(aCur1, 1);
    if (tp < 17) { if (MODE == 1) finishA1(); else finishA0(); }
    __syncthreads();
  }

  // ---- epilogue: fragment-native partials, 128B-coalesced stores ----
  size_t wbase = ((size_t)((b * 64 + h) * 4 + wv)) * (NFR * 4 * 64);
#pragma unroll
  for (int nf = 0; nf < NFR; ++nf)
#pragma unroll
    for (int ri = 0; ri < 4; ++ri)
      par[wbase + (nf * 4 + ri) * 64 + lane] = f2bf(acc[nf][ri]);
}

// ---------------- reduces (fragment-layout input) ----------------
// frag idx(b,h,wv,nf,ri,lane) = ((b*64+h)*4+wv)*(NFR*4*64) + (nf*4+ri)*64+lane
// lane = rq*16+ml; pixel col = wv*16+rq*4+ri; c = nf*16+ml.

// conv1 -> bf16 chlast t1 [bg][pix][c]; NFR=16 (stride 4096)
__global__ __launch_bounds__(256) void reduce_c1(
    const ushort* __restrict__ p0, const ushort* __restrict__ p1,
    const float* __restrict__ bias, ushort* __restrict__ t1) {
  const int N = 8 * 4 * 4096 * 8;   // groups of 8 channels
  for (int i = blockIdx.x * 256 + threadIdx.x; i < N; i += gridDim.x * 256) {
    int cg = i & 7;
    int pix = (i >> 3) & 4095;
    int g = (i >> 15) & 3;
    int b = i >> 17;
    int h = pix >> 6, col = pix & 63;
    int wv = col >> 4, rr = col & 15;
    int rq = rr >> 2, ri = rr & 3;
    int cp = g * 64 + cg * 8;
    int nf = cp >> 4, mlb = cp & 15;
    size_t idx = ((size_t)((b * 64 + h) * 4 + wv)) * 4096 +
                 (nf * 4 + ri) * 64 + rq * 16 + mlb;
    bf16x8 a = *(const bf16x8*)(p0 + idx);
    bf16x8 c = *(const bf16x8*)(p1 + idx);
    bf16x8 o;
#pragma unroll
    for (int j = 0; j < 8; ++j)
      o[j] = (short)f2bf(bf2f((ushort)a[j]) + bf2f((ushort)c[j]) + bias[cp + j]);
    *(bf16x8*)(t1 + ((size_t)(b * 4 + g) * 4096 + pix) * 64 + cg * 8) = o;
  }
}

// conv2 -> f32 planar offsets [b][72][4096]; NFR=8 (stride 2048)
__global__ __launch_bounds__(256) void reduce_c2(
    const ushort* __restrict__ p0, const ushort* __restrict__ p1,
    const float* __restrict__ bias, float* __restrict__ out) {
  const int N = 8 * 72 * 1024;      // groups of 4 pixels
  for (int i = blockIdx.x * 256 + threadIdx.x; i < N; i += gridDim.x * 256) {
    int p4 = i & 1023;
    int r = i >> 10;
    int co = r % 72, b = r / 72;
    int h = p4 >> 4;
    int col0 = (p4 & 15) * 4;
    int wv = col0 >> 4, rq = (col0 >> 2) & 3;
    int nf = co >> 4, ml = co & 15;
    size_t base = ((size_t)((b * 64 + h) * 4 + wv)) * 2048 +
                  nf * 256 + rq * 16 + ml;
    float bv = bias[co];
    float4 o;
    o.x = bf2f(p0[base +   0]) + bf2f(p1[base +   0]) + bv;
    o.y = bf2f(p0[base +  64]) + bf2f(p1[base +  64]) + bv;
    o.z = bf2f(p0[base + 128]) + bf2f(p1[base + 128]) + bv;
    o.w = bf2f(p0[base + 192]) + bf2f(p1[base + 192]) + bv;
    *(float4*)(out + (((size_t)b * 72 + co) << 12) + p4 * 4) = o;
  }
}

// deform -> f32 NCHW + ReLU; NFR=16 (stride 4096)
__global__ __launch_bounds__(256) void reduce_df(
    const ushort* __restrict__ p0, const ushort* __restrict__ p1,
    float* __restrict__ out) {
  const int N = 8 * 256 * 1024;     // groups of 4 pixels
  for (int i = blockIdx.x * 256 + threadIdx.x; i < N; i += gridDim.x * 256) {
    int p4 = i & 1023;
    int co = (i >> 10) & 255;
    int b = i >> 18;
    int h = p4 >> 4;
    int col0 = (p4 & 15) * 4;
    int wv = col0 >> 4, rq = (col0 >> 2) & 3;
    int nf = co >> 4, ml = co & 15;
    size_t base = ((size_t)((b * 64 + h) * 4 + wv)) * 4096 +
                  nf * 256 + rq * 16 + ml;
    float4 o;
    o.x = fmaxf(bf2f(p0[base +   0]) + bf2f(p1[base +   0]), 0.f);
    o.y = fmaxf(bf2f(p0[base +  64]) + bf2f(p1[base +  64]), 0.f);
    o.z = fmaxf(bf2f(p0[base + 128]) + bf2f(p1[base + 128]), 0.f);
    o.w = fmaxf(bf2f(p0[base + 192]) + bf2f(p1[base + 192]), 0.f);
    *(float4*)(out + (((size_t)b * 256 + co) << 12) + p4 * 4) = o;
  }
}

extern "C" void kernel_launch(void* const* d_in, const int* in_sizes, int n_in,
                              void* d_out, int out_size, void* d_ws, size_t ws_size,
                              hipStream_t stream) {
  const float* x  = (const float*)d_in[0];
  const float* w1 = (const float*)d_in[1];
  const float* b1 = (const float*)d_in[2];
  const float* w2 = (const float*)d_in[3];
  const float* b2 = (const float*)d_in[4];
  const float* wd = (const float*)d_in[5];

  char* wsb = (char*)d_ws;
  float*  off_buf = (float*)wsb;                    //  9,437,184 B
  ushort* xt      = (ushort*)(wsb + 9437184);       // 16,777,216 B
  ushort* wt1     = (ushort*)(wsb + 26214400);      //  1,179,648 B
  ushort* wt2     = (ushort*)(wsb + 27394048);      //    589,824 B
  ushort* wtd     = (ushort*)(wsb + 27983872);      //  1,179,648 B
  ushort* par0    = (ushort*)(wsb + 29163520);      // 16,777,216 B
  ushort* par1    = (ushort*)(wsb + 45940736);      // 16,777,216 B -> 62.7 MB

  prep_weights<<<2048, 256, 0, stream>>>(w1, w2, wd, wt1, wt2, wtd);
  transpose_x<<<2048, 256, 0, stream>>>(x, xt);

  ushort* t1 = (ushort*)d_out;   // bf16 chlast t1 lives in d_out until deform

  // conv1: xt -> frag partials; NFR=16
  fa_mfma10<0, 16><<<1024, 256, 0, stream>>>(xt, nullptr, wt1, par0, par1);
  reduce_c1<<<2048, 256, 0, stream>>>(par0, par1, b1, t1);

  // conv2: t1 -> frag partials; NFR=8 (co padded to 128, zero weights)
  fa_mfma10<0, 8><<<1024, 256, 0, stream>>>(t1, nullptr, wt2, par0, par1);
  reduce_c2<<<1024, 256, 0, stream>>>(par0, par1, b2, off_buf);

  // deform: xt + offsets -> frag partials; NFR=16
  fa_mfma10<1, 16><<<1024, 256, 0, stream>>>(xt, off_buf, wtd, par0, par1);
  reduce_df<<<2048, 256, 0, stream>>>(par0, par1, (float*)d_out);
}

// Round 13
// 214.484 us; speedup vs baseline: 1.1011x; 1.1011x over previous
//
#include <hip/hip_runtime.h>
#include <hip/hip_bf16.h>

// FeatureAdaption R13: R12's verified components WITHOUT K-split:
// 4-wave/256-thr blocks, BK=32 dbuf, [p][co][e] conflict-free LDS, direct
// epilogues (no partials, no reduce kernels), launch_bounds(256,4) -> 4 blk/CU.
// conv1(256->256) -> conv2(256->72)=offsets -> deform conv v1 + ReLU.
// B=8, C=256, H=W=64, dg=4, K=9 taps, K_total=2304 = 72 subtiles of 32.

typedef __attribute__((ext_vector_type(8))) short bf16x8;
typedef __attribute__((ext_vector_type(4))) float f32x4;

static __device__ __forceinline__ ushort f2bf(float f) {
  __hip_bfloat16 h = __float2bfloat16(f);
  return *reinterpret_cast<ushort*>(&h);
}
static __device__ __forceinline__ float bf2f(ushort u) {
  union { uint u32; float f; } cv;
  cv.u32 = ((uint)u) << 16;
  return cv.f;
}

// ---------------- weight prep: [tk 72][p 4][co][e 8] bf16 (R12 verbatim) -----
// k within subtile = p*8+e; channel-in-tap cc = (tk&1)*32 + p*8 + e.
// conv : tap ti = tk>>1 = kk*4+chunk  (ci = chunk*64+cc)
// deform: tap ti = g*9+kkt            (c = cc within group)
__global__ __launch_bounds__(256) void prep_weights(
    const float* __restrict__ w1, const float* __restrict__ w2,
    const float* __restrict__ wd,
    ushort* __restrict__ wt1, ushort* __restrict__ wt2,
    ushort* __restrict__ wtd) {
  const int N1 = 72 * 4 * 256 * 8;   // 589824
  const int N2 = 72 * 4 * 128 * 8;   // 294912 (co padded 72->128, zeros)
  const int N3 = 72 * 4 * 256 * 8;   // 589824
  int total = N1 + N2 + N3;
  for (int i = blockIdx.x * 256 + threadIdx.x; i < total; i += gridDim.x * 256) {
    if (i < N1) {
      int e = i & 7, co = (i >> 3) & 255, p = (i >> 11) & 3, tk = i >> 13;
      int ti = tk >> 1, half = tk & 1;
      int kk = ti >> 2, ch = ti & 3;
      int cc = half * 32 + p * 8 + e;
      wt1[i] = f2bf(w1[(co * 256 + ch * 64 + cc) * 9 + kk]);
    } else if (i < N1 + N2) {
      int d = i - N1;
      int e = d & 7, co = (d >> 3) & 127, p = (d >> 10) & 3, tk = d >> 12;
      int ti = tk >> 1, half = tk & 1;
      int kk = ti >> 2, ch = ti & 3;
      int cc = half * 32 + p * 8 + e;
      wt2[d] = (co < 72) ? f2bf(w2[(co * 256 + ch * 64 + cc) * 9 + kk])
                         : (ushort)0;
    } else {
      int d = i - N1 - N2;
      int e = d & 7, co = (d >> 3) & 255, p = (d >> 11) & 3, tk = d >> 13;
      int ti = tk >> 1, half = tk & 1;
      int g = ti / 9, kkt = ti - g * 9;
      int c = half * 32 + p * 8 + e;
      wtd[d] = f2bf(wd[(co * 256 + g * 64 + c) * 9 + kkt]);
    }
  }
}

// ---------------- x -> channel-last grouped bf16 (verified R3-R12) -----------
__global__ __launch_bounds__(256) void transpose_x(
    const float* __restrict__ x, ushort* __restrict__ xt) {
  int id = blockIdx.x;
  int y = id & 63, bg = id >> 6;
  int c = threadIdx.x & 63, xi = threadIdx.x >> 6;
  const float* ip = x + (((size_t)bg) << 18) + ((size_t)c << 12) + y * 64;
  ushort* op = xt + (((size_t)bg) << 18) + (size_t)y * 4096 + c;
#pragma unroll
  for (int j = 0; j < 16; ++j) {
    int xx = xi * 16 + j;
    op[(size_t)xx * 64] = f2bf(ip[xx]);
  }
}

// ---------------- 16x16 MFMA kernel: full K, BK=32, direct epilogue ----------
// Grid 512 = 8b x 64h [XCD swizzled -> batch b == XCD id].
// Block: 4 waves x 16px = one h row (64 px); co tile = NFR*16 (all waves).
// 36 taps = 72 BK=32 subtiles; LDS [p][co][e] dbuf (verified conflict-free).
// A-path pipelined one tap ahead (offsets two ahead) — R7/R12-verified.
// OUTK: 0 = bf16 chlast + bias; 1 = f32 planar + bias (co<co_write);
//       2 = f32 planar NCHW + ReLU.
template <int MODE, int NFR, int OUTK>
__global__ __launch_bounds__(256, 4) void fa_mfma11(
    const ushort* __restrict__ inT,  // [bg][4096 px][64 c] bf16
    const float* __restrict__ off,   // [B][72][64][64] f32 (MODE 1)
    const ushort* __restrict__ wBs,  // [72][4][CO_TILE][8] bf16
    const float* __restrict__ bias,
    void* __restrict__ outp,
    int co_total, int co_write) {
  constexpr int CO_TILE = NFR * 16;
  constexpr int SUB_U = CO_TILE * 32;            // ushorts per subtile
  constexpr int NCALLS = (SUB_U * 2) / 4096;     // 16B x 256thr per call
  constexpr int NRN = (MODE == 1) ? 8 : 2;
  __shared__ __align__(16) ushort Blds[2][SUB_U];

  int id = blockIdx.x;
  int id2 = (id & 7) * 64 + (id >> 3);           // XCD swizzle (512 = 8*64)
  int h = id2 & 63, b = id2 >> 6;                // h [0,64), b [0,8)
  int t = threadIdx.x;
  int wv = t >> 6, lane = t & 63;
  int ml = lane & 15, kc = lane >> 4;
  int pcol = wv * 16 + ml;                       // this lane's pixel column

  auto stage = [&](int sg, int buf) {            // sg = global subtile [0,72)
    const char* src0 = (const char*)wBs + (size_t)sg * (SUB_U * 2) + t * 16;
    ushort* dst0 = &Blds[buf][t * 8];
#pragma unroll
    for (int m = 0; m < NCALLS; ++m) {
      __builtin_amdgcn_global_load_lds(
          (const __attribute__((address_space(1))) void*)(src0 + m * 4096),
          (__attribute__((address_space(3))) void*)(dst0 + m * 2048), 16, 0, 0);
    }
  };

  const bf16x8 bz = {0, 0, 0, 0, 0, 0, 0, 0};
  bf16x8 aCur0, aCur1;                           // tap's two 32-chan frags
  bf16x8 rN[NRN];
  float wsv[4];
  float2 offA;

  // ---- MODE 0: direct conv A-path (verified) ----
  auto issueA0 = [&](int tap) {
    int kk = tap >> 2, chunk = tap & 3;
    int ky = kk / 3, kx = kk - ky * 3;
    int gy = h + ky - 1, gx = pcol + kx - 1;
    bool inb = (gy >= 0) & (gy < 64) & (gx >= 0) & (gx < 64);
    const ushort* p =
        inT + ((((size_t)(b * 4 + chunk) << 12) + gy * 64 + gx) << 6) + kc * 8;
    rN[0] = bz;
    rN[1] = bz;
    if (inb) {
      rN[0] = *(const bf16x8*)p;
      rN[1] = *(const bf16x8*)(p + 32);
    }
  };
  auto finishA0 = [&]() {
    aCur0 = rN[0];
    aCur1 = rN[1];
  };

  // ---- MODE 1: deform A-path (verified) ----
  auto loadOff = [&](int tap) {
    int g = tap / 9, kkt = tap - 9 * (tap / 9);
    int ch = g * 18 + kkt * 2;
    const float* offp = off + (((size_t)b * 72 + ch) << 12) + h * 64 + pcol;
    offA.x = offp[0];
    offA.y = offp[4096];
  };
  auto issueA1 = [&](int tap) {
    int g = tap / 9, kkt = tap - 9 * (tap / 9);
    int ky = kkt / 3, kx = kkt - ky * 3;
    const ushort* base = inT + (((size_t)(b * 4 + g)) << 18) + kc * 8;
    float py = (float)(h + ky - 1) + offA.x;
    float pxf = (float)(pcol + kx - 1) + offA.y;
    float y0f = floorf(py), x0f = floorf(pxf);
    float wy1 = py - y0f, wx1 = pxf - x0f;
    float wy0 = 1.f - wy1, wx0 = 1.f - wx1;
    int y0 = (int)y0f, x0i = (int)x0f;
    int y1 = y0 + 1, x1i = x0i + 1;
    bool vy0 = (y0 >= 0) & (y0 < 64);
    bool vy1 = (y1 >= 0) & (y1 < 64);
    bool vx0 = (x0i >= 0) & (x0i < 64);
    bool vx1 = (x1i >= 0) & (x1i < 64);
    wsv[0] = (vy0 & vx0) ? wy0 * wx0 : 0.f;
    wsv[1] = (vy0 & vx1) ? wy0 * wx1 : 0.f;
    wsv[2] = (vy1 & vx0) ? wy1 * wx0 : 0.f;
    wsv[3] = (vy1 & vx1) ? wy1 * wx1 : 0.f;
    int yc0 = min(max(y0, 0), 63), yc1 = min(max(y1, 0), 63);
    int xc0 = min(max(x0i, 0), 63), xc1 = min(max(x1i, 0), 63);
    const ushort* p00 = base + ((yc0 * 64 + xc0) << 6);
    const ushort* p01 = base + ((yc0 * 64 + xc1) << 6);
    const ushort* p10 = base + ((yc1 * 64 + xc0) << 6);
    const ushort* p11 = base + ((yc1 * 64 + xc1) << 6);
    rN[0] = *(const bf16x8*)p00;
    rN[1] = *(const bf16x8*)(p00 + 32);
    rN[2] = *(const bf16x8*)p01;
    rN[3] = *(const bf16x8*)(p01 + 32);
    rN[4] = *(const bf16x8*)p10;
    rN[5] = *(const bf16x8*)(p10 + 32);
    rN[6] = *(const bf16x8*)p11;
    rN[7] = *(const bf16x8*)(p11 + 32);
  };
  auto finishA1 = [&]() {
    float w00 = wsv[0], w01 = wsv[1], w10 = wsv[2], w11 = wsv[3];
#pragma unroll
    for (int ks = 0; ks < 2; ++ks) {
      bf16x8 q00 = rN[0 + ks], q01 = rN[2 + ks];
      bf16x8 q10 = rN[4 + ks], q11 = rN[6 + ks];
      bf16x8 av;
#pragma unroll
      for (int jj = 0; jj < 8; ++jj) {
        float v = w00 * bf2f((ushort)q00[jj]) + w01 * bf2f((ushort)q01[jj]) +
                  w10 * bf2f((ushort)q10[jj]) + w11 * bf2f((ushort)q11[jj]);
        av[jj] = (short)f2bf(v);
      }
      if (ks == 0) aCur0 = av; else aCur1 = av;
    }
  };

  f32x4 acc[NFR];
#pragma unroll
  for (int j = 0; j < NFR; ++j) acc[j] = (f32x4){0.f, 0.f, 0.f, 0.f};

  auto domfma = [&](bf16x8 a, int buf) {
    __builtin_amdgcn_s_setprio(1);
#pragma unroll
    for (int nf = 0; nf < NFR; ++nf) {
      bf16x8 bq = *(const bf16x8*)&Blds[buf][(kc * CO_TILE + nf * 16 + ml) * 8];
      acc[nf] = __builtin_amdgcn_mfma_f32_16x16x32_bf16(a, bq, acc[nf], 0, 0, 0);
    }
    __builtin_amdgcn_s_setprio(0);
  };

  // prologue: A(0) built, subtile 0 staged
  if (MODE == 1) {
    loadOff(0);
    issueA1(0);
    loadOff(1);
    finishA1();
  } else {
    issueA0(0);
    finishA0();
  }
  stage(0, 0);
  __syncthreads();

  for (int tp = 0; tp < 36; ++tp) {
    // even phase: subtile 2tp (buf0); prefetch subtile 2tp+1 and next tap's A
    if (2 * tp + 1 < 72) stage(2 * tp + 1, 1);
    if (tp < 35) { if (MODE == 1) issueA1(tp + 1); else issueA0(tp + 1); }
    if (MODE == 1 && tp < 34) loadOff(tp + 2);
    domfma(aCur0, 0);
    __syncthreads();
    // odd phase: subtile 2tp+1 (buf1); prefetch subtile 2tp+2; finish next A
    if (2 * tp + 2 < 72) stage(2 * tp + 2, 0);
    domfma(aCur1, 1);
    if (tp < 35) { if (MODE == 1) finishA1(); else finishA0(); }
    __syncthreads();
  }

  // ---- direct epilogue: D col = lane&15 (co), row = (lane>>4)*4+ri (px) ----
  int rq = lane >> 4;
#pragma unroll
  for (int nf = 0; nf < NFR; ++nf) {
    int cog = nf * 16 + ml;
    if (cog < co_write) {
      float bv = (OUTK == 2) ? 0.f : bias[cog];
#pragma unroll
      for (int ri = 0; ri < 4; ++ri) {
        int pxe = wv * 16 + rq * 4 + ri;
        float v = acc[nf][ri] + bv;
        if (OUTK == 0) {
          int g_out = cog >> 6, ci = cog & 63;
          ((ushort*)outp)[((((size_t)(b * 4 + g_out) << 12) + h * 64 + pxe) << 6) + ci] =
              f2bf(v);
        } else if (OUTK == 1) {
          ((float*)outp)[(((size_t)b * co_total + cog) << 12) + h * 64 + pxe] = v;
        } else {
          ((float*)outp)[(((size_t)b * co_total + cog) << 12) + h * 64 + pxe] =
              fmaxf(v, 0.f);
        }
      }
    }
  }
}

extern "C" void kernel_launch(void* const* d_in, const int* in_sizes, int n_in,
                              void* d_out, int out_size, void* d_ws, size_t ws_size,
                              hipStream_t stream) {
  const float* x  = (const float*)d_in[0];
  const float* w1 = (const float*)d_in[1];
  const float* b1 = (const float*)d_in[2];
  const float* w2 = (const float*)d_in[3];
  const float* b2 = (const float*)d_in[4];
  const float* wd = (const float*)d_in[5];

  char* wsb = (char*)d_ws;
  float*  off_buf = (float*)wsb;                    //  9,437,184 B
  ushort* xt      = (ushort*)(wsb + 9437184);       // 16,777,216 B
  ushort* wt1     = (ushort*)(wsb + 26214400);      //  1,179,648 B
  ushort* wt2     = (ushort*)(wsb + 27394048);      //    589,824 B
  ushort* wtd     = (ushort*)(wsb + 27983872);      //  1,179,648 B -> 29.2 MB

  prep_weights<<<2048, 256, 0, stream>>>(w1, w2, wd, wt1, wt2, wtd);
  transpose_x<<<2048, 256, 0, stream>>>(x, xt);

  ushort* t1 = (ushort*)d_out;   // bf16 chlast t1 lives in d_out until deform

  // conv1: xt -> t1 (bf16 chlast, +bias); NFR=16, LDS 2x16KB
  fa_mfma11<0, 16, 0><<<512, 256, 0, stream>>>(
      xt, nullptr, wt1, b1, t1, 256, 256);

  // conv2: t1 -> offsets (f32 planar, +bias, co<72); NFR=8, LDS 2x8KB
  fa_mfma11<0, 8, 1><<<512, 256, 0, stream>>>(
      t1, nullptr, wt2, b2, off_buf, 72, 72);

  // deform + relu: xt, offsets -> d_out (f32 NCHW); NFR=16
  fa_mfma11<1, 16, 2><<<512, 256, 0, stream>>>(
      xt, off_buf, wtd, nullptr, d_out, 256, 256);
}